// Round 3
// baseline (293.523 us; speedup 1.0000x reference)
//
#include <hip/hip_runtime.h>

#define DHW    65536
#define NCH    256
#define NNODE  7
#define NHID   128
#define NBATCH 2

typedef float vf4 __attribute__((ext_vector_type(4)));

__device__ inline float4 f4fma(float4 v, float w, float4 a) {
    a.x = fmaf(v.x, w, a.x); a.y = fmaf(v.y, w, a.y);
    a.z = fmaf(v.z, w, a.z); a.w = fmaf(v.w, w, a.w);
    return a;
}

// ---------------------------------------------------------------------------
// Prep: nwt[b][c][8] = new_weight^T padded; n2g[b][8]; w1p[c][8] padded.
// ---------------------------------------------------------------------------
__global__ void prep_kernel(const float* __restrict__ inp,
                            const float* __restrict__ nfh,
                            const float* __restrict__ weight,
                            const float* __restrict__ w1,
                            float* __restrict__ nwt,
                            float* __restrict__ n2g,
                            float* __restrict__ w1p)
{
    const int bn = blockIdx.x;
    const int b  = bn / NNODE;
    const int n  = bn % NNODE;
    const int t  = threadIdx.x;
    const float* ih = inp + (b * NNODE + n) * NHID;

    float acc = 0.f;
    #pragma unroll 8
    for (int h = 0; h < NHID; ++h)
        acc = fmaf(ih[h], weight[h * NCH + t], acc);
    nwt[(b * NCH + t) * 8 + n] = acc;

    if (bn == 0) {
        #pragma unroll
        for (int k = 0; k < NNODE; ++k) w1p[t * 8 + k] = w1[t * NNODE + k];
        w1p[t * 8 + 7] = 0.f;
    }

    __shared__ float red[NHID];
    if (t < NHID) red[t] = ih[t] * nfh[t];
    __syncthreads();
    for (int s = NHID / 2; s > 0; s >>= 1) {
        if (t < s) red[t] += red[t + s];
        __syncthreads();
    }
    if (t == 0) n2g[b * 8 + n] = red[0];
}

// ---------------------------------------------------------------------------
// Main: identical to the round-0 best (242.7 us). Launched TWICE this round
// as a timing probe: the dur_us delta vs 242.7 measures one execution, and
// if it exceeds the ~78 us fills it will surface in the top-5 counters.
// Idempotent: reads rf/workspace, writes the same out both times.
// ---------------------------------------------------------------------------
__global__ __launch_bounds__(256, 2)
void main_kernel(const float* __restrict__ rf,    // [2][256][65536]
                 const float* __restrict__ w1p,   // [256][8]
                 const float* __restrict__ nwt,   // [2][256][8]
                 const float* __restrict__ n2g,   // [2][8]
                 float* __restrict__ out)         // [2][256][65536]
{
    __shared__ float4 red[NNODE][4][64];   // 28 KiB

    const int t    = threadIdx.x;
    const int lane = t & 63;
    const int wv   = __builtin_amdgcn_readfirstlane(t >> 6);  // 0..3 uniform
    const int blk  = blockIdx.x;            // 0..511
    const int b    = blk >> 8;
    const int i4   = ((blk & 255) << 6) + lane;   // float4 idx in plane [0,16384)
    const int c0   = wv << 6;

    // ---- Phase 1: partial scores over this wave's 64 channels -----------
    const vf4* rp = (const vf4*)rf + (((size_t)(b * NCH + c0)) << 14) + i4;
    const float4* wq = (const float4*)w1p + (c0 << 1);

    float4 a0 = {0,0,0,0}, a1 = {0,0,0,0}, a2 = {0,0,0,0}, a3 = {0,0,0,0};
    float4 a4 = {0,0,0,0}, a5 = {0,0,0,0}, a6 = {0,0,0,0};

    #pragma unroll 8
    for (int ci = 0; ci < 64; ++ci) {
        vf4 vv = __builtin_nontemporal_load(&rp[(size_t)ci << 14]);
        float4 v = make_float4(vv.x, vv.y, vv.z, vv.w);
        float4 wa = wq[ci * 2];       // uniform -> scalar loads
        float4 wb = wq[ci * 2 + 1];
        a0 = f4fma(v, wa.x, a0);
        a1 = f4fma(v, wa.y, a1);
        a2 = f4fma(v, wa.z, a2);
        a3 = f4fma(v, wa.w, a3);
        a4 = f4fma(v, wb.x, a4);
        a5 = f4fma(v, wb.y, a5);
        a6 = f4fma(v, wb.z, a6);
    }

    red[0][wv][lane] = a0;  red[1][wv][lane] = a1;  red[2][wv][lane] = a2;
    red[3][wv][lane] = a3;  red[4][wv][lane] = a4;  red[5][wv][lane] = a5;
    red[6][wv][lane] = a6;
    __syncthreads();

    // ---- Cross-wave reduce + softmax (all waves need full attn) ---------
    const float* n2 = n2g + b * 8;   // uniform -> scalar loads
    float4 s[NNODE];
    #pragma unroll
    for (int n = 0; n < NNODE; ++n) {
        float4 r = red[n][0][lane];
        #pragma unroll
        for (int w = 1; w < 4; ++w) {
            float4 q = red[n][w][lane];
            r.x += q.x; r.y += q.y; r.z += q.z; r.w += q.w;
        }
        r.x += n2[n]; r.y += n2[n]; r.z += n2[n]; r.w += n2[n];
        s[n] = r;
    }
    float4 m = s[0];
    #pragma unroll
    for (int n = 1; n < NNODE; ++n) {
        m.x = fmaxf(m.x, s[n].x); m.y = fmaxf(m.y, s[n].y);
        m.z = fmaxf(m.z, s[n].z); m.w = fmaxf(m.w, s[n].w);
    }
    float4 sum = {0,0,0,0};
    float4 e[NNODE];
    #pragma unroll
    for (int n = 0; n < NNODE; ++n) {
        e[n].x = __expf(s[n].x - m.x); e[n].y = __expf(s[n].y - m.y);
        e[n].z = __expf(s[n].z - m.z); e[n].w = __expf(s[n].w - m.w);
        sum.x += e[n].x; sum.y += e[n].y; sum.z += e[n].z; sum.w += e[n].w;
    }
    float4 inv = make_float4(1.f/sum.x, 1.f/sum.y, 1.f/sum.z, 1.f/sum.w);
    #pragma unroll
    for (int n = 0; n < NNODE; ++n) {
        e[n].x *= inv.x; e[n].y *= inv.y; e[n].z *= inv.z; e[n].w *= inv.w;
    }

    // ---- Phase 2: this wave's 64 output channels ------------------------
    const float4* nq = (const float4*)nwt + ((b * NCH + c0) << 1);  // uniform
    vf4* op = (vf4*)out + (((size_t)(b * NCH + c0)) << 14) + i4;
    #pragma unroll 8
    for (int ci = 0; ci < 64; ++ci) {
        float4 na = nq[ci * 2];       // uniform -> scalar loads
        float4 nb = nq[ci * 2 + 1];
        float4 o = {0,0,0,0};
        o = f4fma(e[0], na.x, o);
        o = f4fma(e[1], na.y, o);
        o = f4fma(e[2], na.z, o);
        o = f4fma(e[3], na.w, o);
        o = f4fma(e[4], nb.x, o);
        o = f4fma(e[5], nb.y, o);
        o = f4fma(e[6], nb.z, o);
        vf4 ov;
        ov.x = fmaxf(o.x, 0.f); ov.y = fmaxf(o.y, 0.f);
        ov.z = fmaxf(o.z, 0.f); ov.w = fmaxf(o.w, 0.f);
        __builtin_nontemporal_store(ov, &op[(size_t)ci << 14]);
    }
}

extern "C" void kernel_launch(void* const* d_in, const int* in_sizes, int n_in,
                              void* d_out, int out_size, void* d_ws, size_t ws_size,
                              hipStream_t stream) {
    const float* inp = (const float*)d_in[0];   // (1,2,7,128)
    const float* rf  = (const float*)d_in[1];   // (2,256,16,64,64)
    const float* w1  = (const float*)d_in[2];   // (256,7)
    const float* nfh = (const float*)d_in[3];   // (128,1)
    const float* wgt = (const float*)d_in[4];   // (128,256)
    float* out = (float*)d_out;

    float* nwt = (float*)d_ws;                  // [2][256][8]
    float* n2g = nwt + NBATCH * NCH * 8;        // [2][8]
    float* w1p = n2g + NBATCH * 8;              // [256][8]

    prep_kernel<<<NBATCH * NNODE, 256, 0, stream>>>(inp, nfh, wgt, w1, nwt, n2g, w1p);
    // PROBE: launched twice (idempotent). dur_us delta vs 242.7 = one
    // main_kernel execution; if >= ~78 us it also surfaces in top-5 counters.
    main_kernel<<<NBATCH * 256, 256, 0, stream>>>(rf, w1p, nwt, n2g, out);
    main_kernel<<<NBATCH * 256, 256, 0, stream>>>(rf, w1p, nwt, n2g, out);
}

// Round 4
// 242.529 us; speedup vs baseline: 1.2103x; 1.2103x over previous
//
#include <hip/hip_runtime.h>

#define DHW    65536
#define NCH    256
#define NNODE  7
#define NHID   128
#define NBATCH 2

typedef float vf4 __attribute__((ext_vector_type(4)));

__device__ inline float4 f4fma(float4 v, float w, float4 a) {
    a.x = fmaf(v.x, w, a.x); a.y = fmaf(v.y, w, a.y);
    a.z = fmaf(v.z, w, a.z); a.w = fmaf(v.w, w, a.w);
    return a;
}

// ---------------------------------------------------------------------------
// Prep: nwt[b][c][8] = new_weight^T padded; n2g[b][8]; w1p[c][8] padded.
// ---------------------------------------------------------------------------
__global__ void prep_kernel(const float* __restrict__ inp,
                            const float* __restrict__ nfh,
                            const float* __restrict__ weight,
                            const float* __restrict__ w1,
                            float* __restrict__ nwt,
                            float* __restrict__ n2g,
                            float* __restrict__ w1p)
{
    const int bn = blockIdx.x;
    const int b  = bn / NNODE;
    const int n  = bn % NNODE;
    const int t  = threadIdx.x;
    const float* ih = inp + (b * NNODE + n) * NHID;

    float acc = 0.f;
    #pragma unroll 8
    for (int h = 0; h < NHID; ++h)
        acc = fmaf(ih[h], weight[h * NCH + t], acc);
    nwt[(b * NCH + t) * 8 + n] = acc;

    if (bn == 0) {
        #pragma unroll
        for (int k = 0; k < NNODE; ++k) w1p[t * 8 + k] = w1[t * NNODE + k];
        w1p[t * 8 + 7] = 0.f;
    }

    __shared__ float red[NHID];
    if (t < NHID) red[t] = ih[t] * nfh[t];
    __syncthreads();
    for (int s = NHID / 2; s > 0; s >>= 1) {
        if (t < s) red[t] += red[t + s];
        __syncthreads();
    }
    if (t == 0) n2g[b * 8 + n] = red[0];
}

// ---------------------------------------------------------------------------
// Main: grid 1024 (2 batches x 512 col-groups of 32 float4), 256 thr,
// __launch_bounds__(256,3): 4 blocks/CU of work vs 3 resident -> generation
// pipelining (reads of a fresh block overlap writes of a draining one),
// 12 waves/CU steady state. Lane split: half = lane>>5 (channel parity),
// col = lane&31; each load/store is two coalesced 512B segments. Wave w
// covers channels [64w,64w+64) in 32 iters of 2. Coefficients staged in LDS.
// ---------------------------------------------------------------------------
__global__ __launch_bounds__(256, 3)
void main_kernel(const float* __restrict__ rf,    // [2][256][65536]
                 const float* __restrict__ w1p,   // [256][8]
                 const float* __restrict__ nwt,   // [2][256][8]
                 const float* __restrict__ n2g,   // [2][8]
                 float* __restrict__ out)         // [2][256][65536]
{
    __shared__ float4 w1l[512];              // 8 KiB  [c][0..1]
    __shared__ float4 nwl[512];              // 8 KiB  [c][0..1]
    __shared__ float4 red[NNODE][4][32];     // 14 KiB

    const int t    = threadIdx.x;
    const int lane = t & 63;
    const int wv   = __builtin_amdgcn_readfirstlane(t >> 6);  // 0..3 uniform
    const int blk  = blockIdx.x;             // 0..1023
    const int b    = blk >> 9;
    const int g    = blk & 511;              // column group (32 float4)
    const int col  = lane & 31;
    const int half = lane >> 5;              // channel parity
    const int c0   = (wv << 6) + half;       // this lane's first channel
    const int base4 = (g << 5) + col;        // f4 offset within plane

    // ---- Stage coefficients to LDS (coalesced, once per block) ----------
    {
        const float4* wsrc = (const float4*)w1p;
        const float4* nsrc = (const float4*)(nwt + b * NCH * 8);
        w1l[t]       = wsrc[t];
        w1l[t + 256] = wsrc[t + 256];
        nwl[t]       = nsrc[t];
        nwl[t + 256] = nsrc[t + 256];
    }
    __syncthreads();

    // ---- Phase 1: partial scores, 2 channels/iter (2x512B segments) -----
    const vf4* rp = (const vf4*)rf + (((size_t)(b * NCH + c0)) << 14) + base4;

    float4 a0 = {0,0,0,0}, a1 = {0,0,0,0}, a2 = {0,0,0,0}, a3 = {0,0,0,0};
    float4 a4 = {0,0,0,0}, a5 = {0,0,0,0}, a6 = {0,0,0,0};

    #pragma unroll 8
    for (int ci = 0; ci < 32; ++ci) {
        vf4 vv = __builtin_nontemporal_load(&rp[(size_t)(ci * 2) << 14]);
        float4 v = make_float4(vv.x, vv.y, vv.z, vv.w);
        const int c = c0 + ci * 2;            // uniform per half-wave
        float4 wa = w1l[c * 2];               // LDS broadcast
        float4 wb = w1l[c * 2 + 1];
        a0 = f4fma(v, wa.x, a0);
        a1 = f4fma(v, wa.y, a1);
        a2 = f4fma(v, wa.z, a2);
        a3 = f4fma(v, wa.w, a3);
        a4 = f4fma(v, wb.x, a4);
        a5 = f4fma(v, wb.y, a5);
        a6 = f4fma(v, wb.z, a6);
    }

    // combine the two channel-parities (lane l <-> l^32 hold same column)
    #pragma unroll
    for (int k = 0; k < 1; ++k) { }  // (keeps clang from reordering oddly)
    a0.x += __shfl_xor(a0.x, 32); a0.y += __shfl_xor(a0.y, 32);
    a0.z += __shfl_xor(a0.z, 32); a0.w += __shfl_xor(a0.w, 32);
    a1.x += __shfl_xor(a1.x, 32); a1.y += __shfl_xor(a1.y, 32);
    a1.z += __shfl_xor(a1.z, 32); a1.w += __shfl_xor(a1.w, 32);
    a2.x += __shfl_xor(a2.x, 32); a2.y += __shfl_xor(a2.y, 32);
    a2.z += __shfl_xor(a2.z, 32); a2.w += __shfl_xor(a2.w, 32);
    a3.x += __shfl_xor(a3.x, 32); a3.y += __shfl_xor(a3.y, 32);
    a3.z += __shfl_xor(a3.z, 32); a3.w += __shfl_xor(a3.w, 32);
    a4.x += __shfl_xor(a4.x, 32); a4.y += __shfl_xor(a4.y, 32);
    a4.z += __shfl_xor(a4.z, 32); a4.w += __shfl_xor(a4.w, 32);
    a5.x += __shfl_xor(a5.x, 32); a5.y += __shfl_xor(a5.y, 32);
    a5.z += __shfl_xor(a5.z, 32); a5.w += __shfl_xor(a5.w, 32);
    a6.x += __shfl_xor(a6.x, 32); a6.y += __shfl_xor(a6.y, 32);
    a6.z += __shfl_xor(a6.z, 32); a6.w += __shfl_xor(a6.w, 32);

    if (half == 0) {
        red[0][wv][col] = a0;  red[1][wv][col] = a1;  red[2][wv][col] = a2;
        red[3][wv][col] = a3;  red[4][wv][col] = a4;  red[5][wv][col] = a5;
        red[6][wv][col] = a6;
    }
    __syncthreads();

    // ---- Cross-wave reduce + softmax (all lanes, per column) ------------
    const float* n2 = n2g + b * 8;   // uniform -> scalar loads
    float4 s[NNODE];
    #pragma unroll
    for (int n = 0; n < NNODE; ++n) {
        float4 r = red[n][0][col];
        #pragma unroll
        for (int w = 1; w < 4; ++w) {
            float4 q = red[n][w][col];
            r.x += q.x; r.y += q.y; r.z += q.z; r.w += q.w;
        }
        r.x += n2[n]; r.y += n2[n]; r.z += n2[n]; r.w += n2[n];
        s[n] = r;
    }
    float4 m = s[0];
    #pragma unroll
    for (int n = 1; n < NNODE; ++n) {
        m.x = fmaxf(m.x, s[n].x); m.y = fmaxf(m.y, s[n].y);
        m.z = fmaxf(m.z, s[n].z); m.w = fmaxf(m.w, s[n].w);
    }
    float4 sum = {0,0,0,0};
    float4 e[NNODE];
    #pragma unroll
    for (int n = 0; n < NNODE; ++n) {
        e[n].x = __expf(s[n].x - m.x); e[n].y = __expf(s[n].y - m.y);
        e[n].z = __expf(s[n].z - m.z); e[n].w = __expf(s[n].w - m.w);
        sum.x += e[n].x; sum.y += e[n].y; sum.z += e[n].z; sum.w += e[n].w;
    }
    float4 inv = make_float4(1.f/sum.x, 1.f/sum.y, 1.f/sum.z, 1.f/sum.w);
    #pragma unroll
    for (int n = 0; n < NNODE; ++n) {
        e[n].x *= inv.x; e[n].y *= inv.y; e[n].z *= inv.z; e[n].w *= inv.w;
    }

    // ---- Phase 2: this wave's 64 output channels, 2/iter ----------------
    vf4* op = (vf4*)out + (((size_t)(b * NCH + c0)) << 14) + base4;
    #pragma unroll 8
    for (int ci = 0; ci < 32; ++ci) {
        const int c = c0 + ci * 2;            // uniform per half-wave
        float4 na = nwl[c * 2];               // LDS broadcast
        float4 nb = nwl[c * 2 + 1];
        float4 o = {0,0,0,0};
        o = f4fma(e[0], na.x, o);
        o = f4fma(e[1], na.y, o);
        o = f4fma(e[2], na.z, o);
        o = f4fma(e[3], na.w, o);
        o = f4fma(e[4], nb.x, o);
        o = f4fma(e[5], nb.y, o);
        o = f4fma(e[6], nb.z, o);
        vf4 ov;
        ov.x = fmaxf(o.x, 0.f); ov.y = fmaxf(o.y, 0.f);
        ov.z = fmaxf(o.z, 0.f); ov.w = fmaxf(o.w, 0.f);
        __builtin_nontemporal_store(ov, &op[(size_t)(ci * 2) << 14]);
    }
}

extern "C" void kernel_launch(void* const* d_in, const int* in_sizes, int n_in,
                              void* d_out, int out_size, void* d_ws, size_t ws_size,
                              hipStream_t stream) {
    const float* inp = (const float*)d_in[0];   // (1,2,7,128)
    const float* rf  = (const float*)d_in[1];   // (2,256,16,64,64)
    const float* w1  = (const float*)d_in[2];   // (256,7)
    const float* nfh = (const float*)d_in[3];   // (128,1)
    const float* wgt = (const float*)d_in[4];   // (128,256)
    float* out = (float*)d_out;

    float* nwt = (float*)d_ws;                  // [2][256][8]
    float* n2g = nwt + NBATCH * NCH * 8;        // [2][8]
    float* w1p = n2g + NBATCH * 8;              // [256][8]

    prep_kernel<<<NBATCH * NNODE, 256, 0, stream>>>(inp, nfh, wgt, w1, nwt, n2g, w1p);
    main_kernel<<<NBATCH * 512, 256, 0, stream>>>(rf, w1p, nwt, n2g, out);
}